// Round 4
// baseline (297.722 us; speedup 1.0000x reference)
//
#include <hip/hip_runtime.h>
#include <hip/hip_bf16.h>

#define E_N 8
#define D_DIM 1024
#define F_DIM 2048
#define T_N 2048
#define NSLOT 4096

typedef unsigned short u16;
typedef unsigned int u32;
typedef unsigned long long u64;
typedef float floatx4 __attribute__((ext_vector_type(4)));
typedef short bf16x8v __attribute__((ext_vector_type(8)));

__device__ __forceinline__ u16 f2bf(float f) {
    union { float f; u32 u; } v; v.f = f;
    u32 r = v.u + 0x7FFFu + ((v.u >> 16) & 1u);   // RNE
    return (u16)(r >> 16);
}

// async global->LDS, 16B per lane; LDS dest = wave-uniform base + lane*16
__device__ __forceinline__ void gll16(const void* g, void* l) {
    __builtin_amdgcn_global_load_lds((const __attribute__((address_space(1))) void*)g,
                                     (__attribute__((address_space(3))) void*)l, 16, 0, 0);
}

// ---------------- Router: softmax -> top2 -> renorm, bucket by expert ----------------
__global__ void router_kernel(const float* __restrict__ gl,
                              int* __restrict__ cnt, int* __restrict__ base,
                              int* __restrict__ slot_tok, float* __restrict__ slot_w) {
    __shared__ int scnt[E_N];
    __shared__ int sbase[E_N];
    const int tid = threadIdx.x;
    if (tid < E_N) scnt[tid] = 0;
    __syncthreads();
    int e0a[8], e1a[8], p0a[8], p1a[8];
    float w0a[8];
#pragma unroll
    for (int i = 0; i < 8; ++i) {
        const int t = tid + i * 256;
        const float4* gp = (const float4*)(gl + (size_t)t * E_N);
        const float4 x0 = gp[0], x1 = gp[1];
        float l[E_N] = {x0.x, x0.y, x0.z, x0.w, x1.x, x1.y, x1.z, x1.w};
        int e0 = 0; float m0 = l[0];
#pragma unroll
        for (int e = 1; e < E_N; ++e) if (l[e] > m0) { m0 = l[e]; e0 = e; }
        int e1 = -1; float m1 = -1e30f;
#pragma unroll
        for (int e = 0; e < E_N; ++e) if (e != e0 && l[e] > m1) { m1 = l[e]; e1 = e; }
        const float p = __expf(m1 - m0);       // <= 1
        w0a[i] = 1.0f / (1.0f + p);
        e0a[i] = e0; e1a[i] = e1;
        p0a[i] = atomicAdd(&scnt[e0], 1);
        p1a[i] = atomicAdd(&scnt[e1], 1);
    }
    __syncthreads();
    if (tid == 0) {
        int s = 0;
        for (int e = 0; e < E_N; ++e) { sbase[e] = s; base[e] = s; cnt[e] = scnt[e]; s += scnt[e]; }
    }
    __syncthreads();
#pragma unroll
    for (int i = 0; i < 8; ++i) {
        const int t = tid + i * 256;
        const int s0 = sbase[e0a[i]] + p0a[i];
        const int s1 = sbase[e1a[i]] + p1a[i];
        slot_tok[s0] = t; slot_tok[s1] = t;
        slot_w[s0] = w0a[i]; slot_w[s1] = 1.0f - w0a[i];
    }
}

// ---------------- cvt+transpose tile (64x64) via LDS, b64 writes/reads ----------------
// LT: 64 rows (c) x 72 elems (144 B) ; element (c,r) at byte c*144 + ((r>>2)^((c>>2)&15))*8 + (r&3)*2
__device__ __forceinline__ void cvt_tile(const float* __restrict__ src, u16* __restrict__ dst,
                                         int R, int C, int tr, int tc, int e, char* LT) {
    const int r0 = tr << 6, c0 = tc << 6;
    const int t = threadIdx.x;
    const int rowq = t >> 4, col4 = t & 15;
    const float* sp = src + (size_t)e * R * C + (size_t)(r0 + rowq * 4) * C + c0 + col4 * 4;
    float4 v[4];
#pragma unroll
    for (int i = 0; i < 4; ++i) v[i] = *(const float4*)(sp + (size_t)i * C);
    const float* f = (const float*)v;   // f[i*4+j]
#pragma unroll
    for (int j = 0; j < 4; ++j) {
        const int c = col4 * 4 + j;
        u64 pk = (u64)f2bf(f[0 * 4 + j]) | ((u64)f2bf(f[1 * 4 + j]) << 16)
               | ((u64)f2bf(f[2 * 4 + j]) << 32) | ((u64)f2bf(f[3 * 4 + j]) << 48);
        *(u64*)(LT + c * 144 + ((rowq ^ col4) << 3)) = pk;
    }
    __syncthreads();
    u16* dp = dst + (size_t)e * R * C;
#pragma unroll
    for (int i = 0; i < 2; ++i) {
        const int id = i * 256 + t;
        const int c = id >> 3, seg = id & 7;
        const int x = (c >> 2) & 15;
        const u64 lo = *(const u64*)(LT + c * 144 + (((2 * seg) ^ x) << 3));
        const u64 hi = *(const u64*)(LT + c * 144 + (((2 * seg + 1) ^ x) << 3));
        u64 q[2] = {lo, hi};
        *(uint4*)(dp + (size_t)(c0 + c) * R + r0 + seg * 8) = *(const uint4*)q;
    }
}

// ---------------- Prep: cvt W1^T, cvt W2^T, gather X (fused) ----------------
__global__ __launch_bounds__(256) void prep_kernel(const float* __restrict__ W1,
                                                   const float* __restrict__ W2,
                                                   const float* __restrict__ X,
                                                   const int* __restrict__ slot_tok,
                                                   u16* __restrict__ W1T, u16* __restrict__ W2T,
                                                   u16* __restrict__ Xg) {
    __shared__ __align__(16) char LT[64 * 144];
    const int b = blockIdx.x;
    if (b < 4096) {               // W1: R=1024 C=2048, 16x32 tiles/expert
        const int e = b >> 9, rem = b & 511;
        cvt_tile(W1, W1T, D_DIM, F_DIM, rem >> 5, rem & 31, e, LT);
    } else if (b < 8192) {        // W2: R=2048 C=1024, 32x16 tiles/expert
        const int e = (b - 4096) >> 9, rem = (b - 4096) & 511;
        cvt_tile(W2, W2T, F_DIM, D_DIM, rem >> 4, rem & 15, e, LT);
    } else {                      // gather: 4 slots per block
        const int g = b - 8192;
        const int t = threadIdx.x;
        const int s = 4 * g + (t >> 6), lane = t & 63;
        const int tok = slot_tok[s];
        const float* xp = X + (size_t)tok * D_DIM + lane * 4;
        u16* gp = Xg + (size_t)s * D_DIM + lane * 4;
#pragma unroll
        for (int p = 0; p < 4; ++p) {
            const float4 v = *(const float4*)(xp + p * 256);
            union { u16 o[4]; uint2 q; } u;
            u.o[0] = f2bf(v.x); u.o[1] = f2bf(v.y); u.o[2] = f2bf(v.z); u.o[3] = f2bf(v.w);
            *(uint2*)(gp + p * 256) = u.q;
        }
    }
}

// ---------------- Grouped GEMM, m97 structure + T2 swizzle + LDS double-buffer ----------------
// A: [slots][KA] bf16 row-major. B: B^T rows [N][KB] bf16 (per-expert stride D*F).
// Tile 128x128, BK=64, 4 waves (2x2 of 64x64), 16x16x32 MFMA, 4x4 frags.
// One barrier per K-iter: syncthreads (drains vmcnt) -> stage(next into buf^1) -> frags+MFMA(cur).
template<bool G1>
__global__ __launch_bounds__(256) void moe_gemm_kernel(
        const u16* __restrict__ A, const u16* __restrict__ B,
        const int* __restrict__ cnt, const int* __restrict__ basep,
        const int* __restrict__ slot_tok, const float* __restrict__ slot_w,
        u16* __restrict__ hout, float* __restrict__ out) {
    constexpr int KA = G1 ? D_DIM : F_DIM;   // A row stride (elements)
    constexpr int KB = KA;                   // B^T row stride
    constexpr int KIT = 16;                  // 1024/64 per (split-)K range
    const int e  = G1 ? blockIdx.z : (blockIdx.z >> 1);
    const int kh = G1 ? 0 : (blockIdx.z & 1);
    const int mt = blockIdx.y;
    const int nt = blockIdx.x;
    const int cnt_e = cnt[e];
    if (mt * 128 >= cnt_e) return;
    const int m0 = basep[e] + mt * 128;
    const int vm = cnt_e - mt * 128;

    __shared__ __align__(16) u16 Alds[2][8192];
    __shared__ __align__(16) u16 Blds[2][8192];

    const int tid = threadIdx.x;
    const int wid = tid >> 6, lane = tid & 63;
    const int l3 = lane >> 3, l7 = lane & 7;
    const int stgRow = wid * 8 + l3;               // +c*32 per chunk
    const int stgCol = ((l7 ^ l3) << 3);           // pre-swizzled source col (elements)

    const u16* aS = A + (size_t)(m0 + stgRow) * KA + kh * (F_DIM / 2) + stgCol;
    const u16* bS = B + (size_t)e * ((size_t)D_DIM * F_DIM)
                      + (size_t)(nt * 128 + stgRow) * KB + kh * (F_DIM / 2) + stgCol;

    const int wm = (wid >> 1) * 64, wn = (wid & 1) * 64;
    const int lr = lane & 15, lq = lane >> 4;
    const int aoff = (wm + lr) * 64;               // + mi*1024 + sw
    const int boff = (wn + lr) * 64;
    const int sw0 = ((lq)     ^ l7) << 3;          // k-slice 0 swizzled slot
    const int sw1 = ((lq + 4) ^ l7) << 3;          // k-slice 1

    floatx4 acc[4][4];
    const floatx4 zero = {0.f, 0.f, 0.f, 0.f};
#pragma unroll
    for (int i = 0; i < 4; ++i)
#pragma unroll
        for (int j = 0; j < 4; ++j) acc[i][j] = zero;

    auto stage = [&](int buf, int kt) {
        const int ko = kt * 64;
#pragma unroll
        for (int c = 0; c < 4; ++c) {
            gll16(aS + ko + (size_t)(c * 32) * KA, &Alds[buf][c * 2048 + wid * 512]);
            gll16(bS + ko + (size_t)(c * 32) * KB, &Blds[buf][c * 2048 + wid * 512]);
        }
    };

    stage(0, 0);
    int cur = 0;
    for (int kt = 0; kt < KIT; ++kt) {
        __syncthreads();               // own vmcnt drained -> all waves' buf[cur] staged & prior reads done
        if (kt + 1 < KIT) stage(cur ^ 1, kt + 1);   // loads fly under the MFMAs below
#pragma unroll
        for (int ks = 0; ks < 2; ++ks) {
            const int sw = ks ? sw1 : sw0;
            bf16x8v af[4], bfv[4];
#pragma unroll
            for (int mi = 0; mi < 4; ++mi) af[mi]  = *(const bf16x8v*)&Alds[cur][aoff + mi * 1024 + sw];
#pragma unroll
            for (int ni = 0; ni < 4; ++ni) bfv[ni] = *(const bf16x8v*)&Blds[cur][boff + ni * 1024 + sw];
#pragma unroll
            for (int mi = 0; mi < 4; ++mi)
#pragma unroll
                for (int ni = 0; ni < 4; ++ni)
                    acc[mi][ni] = __builtin_amdgcn_mfma_f32_16x16x32_bf16(af[mi], bfv[ni], acc[mi][ni], 0, 0, 0);
        }
        cur ^= 1;
    }

    if constexpr (G1) {
        // h = slot_w * silu(acc)  (weight folded here so gemm2 can atomically combine)
#pragma unroll
        for (int mi = 0; mi < 4; ++mi)
#pragma unroll
            for (int r = 0; r < 4; ++r) {
                const int rl = wm + mi * 16 + lq * 4 + r;
                if (rl < vm) {
                    const float w = slot_w[m0 + rl];
                    u16* hp = hout + (size_t)(m0 + rl) * F_DIM + nt * 128 + wn + lr;
#pragma unroll
                    for (int ni = 0; ni < 4; ++ni) {
                        const float v = acc[mi][ni][r];
                        hp[ni * 16] = f2bf(w * v / (1.0f + __expf(-v)));
                    }
                }
            }
    } else {
#pragma unroll
        for (int mi = 0; mi < 4; ++mi)
#pragma unroll
            for (int r = 0; r < 4; ++r) {
                const int rl = wm + mi * 16 + lq * 4 + r;
                if (rl < vm) {
                    const int tok = slot_tok[m0 + rl];
                    float* op = out + (size_t)tok * D_DIM + nt * 128 + wn + lr;
#pragma unroll
                    for (int ni = 0; ni < 4; ++ni) atomicAdd(&op[ni * 16], acc[mi][ni][r]);
                }
            }
    }
}

extern "C" void kernel_launch(void* const* d_in, const int* in_sizes, int n_in,
                              void* d_out, int out_size, void* d_ws, size_t ws_size,
                              hipStream_t stream) {
    const float* hidden = (const float*)d_in[0];   // [B,S,D] f32
    const float* gl     = (const float*)d_in[1];   // [T,E]   f32
    const float* W1     = (const float*)d_in[2];   // [E,D,F] f32
    const float* W2     = (const float*)d_in[3];   // [E,F,D] f32
    float* out = (float*)d_out;

    char* ws = (char*)d_ws;
    int* m = (int*)ws;
    int* cnt      = m;
    int* basep    = m + 16;
    int* slot_tok = m + 32;                        // 4096 ints
    float* slot_w = (float*)(m + 32 + 4096);       // 4096 floats   (< 64 KB meta)

    const size_t HBYTES  = (size_t)(NSLOT + 128) * F_DIM * 2;        // 17.3 MB (+slack rows)
    const size_t W1BYTES = (size_t)E_N * D_DIM * F_DIM * 2;          // 33.55 MB
    const size_t XBYTES  = (size_t)(NSLOT + 128) * D_DIM * 2;        // 8.65 MB (+slack)
    u16* h   = (u16*)(ws + (1 << 16));
    u16* W1T = (u16*)(ws + (1 << 16) + HBYTES);
    u16* Xg  = (u16*)(ws + (1 << 16) + HBYTES + W1BYTES);
    u16* W2T = (u16*)(ws + (1 << 16) + HBYTES + W1BYTES + XBYTES);   // total ~93.1 MB

    hipMemsetAsync(d_out, 0, (size_t)out_size * sizeof(float), stream);
    router_kernel<<<1, 256, 0, stream>>>(gl, cnt, basep, slot_tok, slot_w);
    prep_kernel<<<8192 + NSLOT / 4, 256, 0, stream>>>(W1, W2, hidden, slot_tok, W1T, W2T, Xg);
    moe_gemm_kernel<true><<<dim3(F_DIM / 128, 16, E_N), 256, 0, stream>>>(
        Xg, W1T, cnt, basep, slot_tok, slot_w, h, nullptr);
    moe_gemm_kernel<false><<<dim3(D_DIM / 128, 16, E_N * 2), 256, 0, stream>>>(
        h, W2T, cnt, basep, slot_tok, slot_w, nullptr, out);
}

// Round 5
// 266.674 us; speedup vs baseline: 1.1164x; 1.1164x over previous
//
#include <hip/hip_runtime.h>
#include <hip/hip_bf16.h>

#define E_N 8
#define D_DIM 1024
#define F_DIM 2048
#define T_N 2048
#define NSLOT 4096

typedef unsigned short u16;
typedef unsigned int u32;
typedef unsigned long long u64;
typedef float floatx4 __attribute__((ext_vector_type(4)));
typedef short bf16x8v __attribute__((ext_vector_type(8)));

__device__ __forceinline__ u16 f2bf(float f) {
    union { float f; u32 u; } v; v.f = f;
    u32 r = v.u + 0x7FFFu + ((v.u >> 16) & 1u);   // RNE
    return (u16)(r >> 16);
}

// async global->LDS, 16B per lane; LDS dest = wave-uniform base + lane*16
__device__ __forceinline__ void gll16(const void* g, void* l) {
    __builtin_amdgcn_global_load_lds((const __attribute__((address_space(1))) void*)g,
                                     (__attribute__((address_space(3))) void*)l, 16, 0, 0);
}

// ---------------- Router: softmax -> top2 -> renorm, bucket by expert ----------------
__global__ void router_kernel(const float* __restrict__ gl,
                              int* __restrict__ cnt, int* __restrict__ base,
                              int* __restrict__ slot_tok, float* __restrict__ slot_w) {
    __shared__ int scnt[E_N];
    __shared__ int sbase[E_N];
    const int tid = threadIdx.x;
    if (tid < E_N) scnt[tid] = 0;
    __syncthreads();
    int e0a[8], e1a[8], p0a[8], p1a[8];
    float w0a[8];
#pragma unroll
    for (int i = 0; i < 8; ++i) {
        const int t = tid + i * 256;
        const float4* gp = (const float4*)(gl + (size_t)t * E_N);
        const float4 x0 = gp[0], x1 = gp[1];
        float l[E_N] = {x0.x, x0.y, x0.z, x0.w, x1.x, x1.y, x1.z, x1.w};
        int e0 = 0; float m0 = l[0];
#pragma unroll
        for (int e = 1; e < E_N; ++e) if (l[e] > m0) { m0 = l[e]; e0 = e; }
        int e1 = -1; float m1 = -1e30f;
#pragma unroll
        for (int e = 0; e < E_N; ++e) if (e != e0 && l[e] > m1) { m1 = l[e]; e1 = e; }
        const float p = __expf(m1 - m0);       // <= 1
        w0a[i] = 1.0f / (1.0f + p);
        e0a[i] = e0; e1a[i] = e1;
        p0a[i] = atomicAdd(&scnt[e0], 1);
        p1a[i] = atomicAdd(&scnt[e1], 1);
    }
    __syncthreads();
    if (tid == 0) {
        int s = 0;
        for (int e = 0; e < E_N; ++e) { sbase[e] = s; base[e] = s; cnt[e] = scnt[e]; s += scnt[e]; }
    }
    __syncthreads();
#pragma unroll
    for (int i = 0; i < 8; ++i) {
        const int t = tid + i * 256;
        const int s0 = sbase[e0a[i]] + p0a[i];
        const int s1 = sbase[e1a[i]] + p1a[i];
        slot_tok[s0] = t; slot_tok[s1] = t;
        slot_w[s0] = w0a[i]; slot_w[s1] = 1.0f - w0a[i];
    }
}

// ---------------- cvt+transpose tile (64x64) via LDS, b64 writes/reads ----------------
// LT: 64 rows (c) x 72 elems (144 B) ; element (c,r) at byte c*144 + ((r>>2)^((c>>2)&15))*8 + (r&3)*2
__device__ __forceinline__ void cvt_tile(const float* __restrict__ src, u16* __restrict__ dst,
                                         int R, int C, int tr, int tc, int e, char* LT) {
    const int r0 = tr << 6, c0 = tc << 6;
    const int t = threadIdx.x;
    const int rowq = t >> 4, col4 = t & 15;
    const float* sp = src + (size_t)e * R * C + (size_t)(r0 + rowq * 4) * C + c0 + col4 * 4;
    float4 v[4];
#pragma unroll
    for (int i = 0; i < 4; ++i) v[i] = *(const float4*)(sp + (size_t)i * C);
    const float* f = (const float*)v;   // f[i*4+j]
#pragma unroll
    for (int j = 0; j < 4; ++j) {
        const int c = col4 * 4 + j;
        u64 pk = (u64)f2bf(f[0 * 4 + j]) | ((u64)f2bf(f[1 * 4 + j]) << 16)
               | ((u64)f2bf(f[2 * 4 + j]) << 32) | ((u64)f2bf(f[3 * 4 + j]) << 48);
        *(u64*)(LT + c * 144 + ((rowq ^ col4) << 3)) = pk;
    }
    __syncthreads();
    u16* dp = dst + (size_t)e * R * C;
#pragma unroll
    for (int i = 0; i < 2; ++i) {
        const int id = i * 256 + t;
        const int c = id >> 3, seg = id & 7;
        const int x = (c >> 2) & 15;
        const u64 lo = *(const u64*)(LT + c * 144 + (((2 * seg) ^ x) << 3));
        const u64 hi = *(const u64*)(LT + c * 144 + (((2 * seg + 1) ^ x) << 3));
        u64 q[2] = {lo, hi};
        *(uint4*)(dp + (size_t)(c0 + c) * R + r0 + seg * 8) = *(const uint4*)q;
    }
}

// ---------------- Prep: cvt W1^T, cvt W2^T, gather X (fused) ----------------
__global__ __launch_bounds__(256) void prep_kernel(const float* __restrict__ W1,
                                                   const float* __restrict__ W2,
                                                   const float* __restrict__ X,
                                                   const int* __restrict__ slot_tok,
                                                   u16* __restrict__ W1T, u16* __restrict__ W2T,
                                                   u16* __restrict__ Xg) {
    __shared__ __align__(16) char LT[64 * 144];
    const int b = blockIdx.x;
    if (b < 4096) {               // W1: R=1024 C=2048, 16x32 tiles/expert
        const int e = b >> 9, rem = b & 511;
        cvt_tile(W1, W1T, D_DIM, F_DIM, rem >> 5, rem & 31, e, LT);
    } else if (b < 8192) {        // W2: R=2048 C=1024, 32x16 tiles/expert
        const int e = (b - 4096) >> 9, rem = (b - 4096) & 511;
        cvt_tile(W2, W2T, F_DIM, D_DIM, rem >> 4, rem & 15, e, LT);
    } else {                      // gather: 4 slots per block
        const int g = b - 8192;
        const int t = threadIdx.x;
        const int s = 4 * g + (t >> 6), lane = t & 63;
        const int tok = slot_tok[s];
        const float* xp = X + (size_t)tok * D_DIM + lane * 4;
        u16* gp = Xg + (size_t)s * D_DIM + lane * 4;
#pragma unroll
        for (int p = 0; p < 4; ++p) {
            const float4 v = *(const float4*)(xp + p * 256);
            union { u16 o[4]; uint2 q; } u;
            u.o[0] = f2bf(v.x); u.o[1] = f2bf(v.y); u.o[2] = f2bf(v.z); u.o[3] = f2bf(v.w);
            *(uint2*)(gp + p * 256) = u.q;
        }
    }
}

// ---------------- Grouped GEMM, m97 structure + T2 swizzle (single buffer, 2 barriers) ----------------
// A: [slots][KA] bf16 row-major. B: B^T rows [N][KB] bf16 (per-expert stride D*F).
// Tile 128x128, BK=64, 4 waves (2x2 of 64x64), 16x16x32 MFMA, 4x4 frags.
template<bool G1>
__global__ __launch_bounds__(256) void moe_gemm_kernel(
        const u16* __restrict__ A, const u16* __restrict__ B,
        const int* __restrict__ cnt, const int* __restrict__ basep,
        const int* __restrict__ slot_tok, const float* __restrict__ slot_w,
        u16* __restrict__ hout, float* __restrict__ out) {
    constexpr int KA = G1 ? D_DIM : F_DIM;   // A row stride (elements)
    constexpr int KB = KA;                   // B^T row stride
    constexpr int KIT = 16;                  // 1024/64 per (split-)K range
    const int e  = G1 ? blockIdx.z : (blockIdx.z >> 1);
    const int kh = G1 ? 0 : (blockIdx.z & 1);
    const int mt = blockIdx.y;
    const int nt = blockIdx.x;
    const int cnt_e = cnt[e];
    if (mt * 128 >= cnt_e) return;
    const int m0 = basep[e] + mt * 128;
    const int vm = cnt_e - mt * 128;

    __shared__ __align__(16) u16 Alds[8192];
    __shared__ __align__(16) u16 Blds[8192];

    const int tid = threadIdx.x;
    const int wid = tid >> 6, lane = tid & 63;
    const int l3 = lane >> 3, l7 = lane & 7;
    const int stgRow = wid * 8 + l3;               // +c*32 per chunk
    const int stgCol = ((l7 ^ l3) << 3);           // pre-swizzled source col (elements)

    const u16* aS = A + (size_t)(m0 + stgRow) * KA + kh * (F_DIM / 2) + stgCol;
    const u16* bS = B + (size_t)e * ((size_t)D_DIM * F_DIM)
                      + (size_t)(nt * 128 + stgRow) * KB + kh * (F_DIM / 2) + stgCol;

    const int wm = (wid >> 1) * 64, wn = (wid & 1) * 64;
    const int lr = lane & 15, lq = lane >> 4;
    const int aoff = (wm + lr) * 64;               // + mi*1024 + sw
    const int boff = (wn + lr) * 64;
    const int sw0 = ((lq)     ^ l7) << 3;          // k-slice 0 swizzled slot
    const int sw1 = ((lq + 4) ^ l7) << 3;          // k-slice 1

    floatx4 acc[4][4];
    const floatx4 zero = {0.f, 0.f, 0.f, 0.f};
#pragma unroll
    for (int i = 0; i < 4; ++i)
#pragma unroll
        for (int j = 0; j < 4; ++j) acc[i][j] = zero;

    for (int kt = 0; kt < KIT; ++kt) {
#pragma unroll
        for (int c = 0; c < 4; ++c) {
            gll16(aS + (size_t)(c * 32) * KA, &Alds[c * 2048 + wid * 512]);
            gll16(bS + (size_t)(c * 32) * KB, &Blds[c * 2048 + wid * 512]);
        }
        aS += 64; bS += 64;
        __syncthreads();   // drains vmcnt -> LDS ready
#pragma unroll
        for (int ks = 0; ks < 2; ++ks) {
            const int sw = ks ? sw1 : sw0;
            bf16x8v af[4], bfv[4];
#pragma unroll
            for (int mi = 0; mi < 4; ++mi) af[mi]  = *(const bf16x8v*)&Alds[aoff + mi * 1024 + sw];
#pragma unroll
            for (int ni = 0; ni < 4; ++ni) bfv[ni] = *(const bf16x8v*)&Blds[boff + ni * 1024 + sw];
#pragma unroll
            for (int mi = 0; mi < 4; ++mi)
#pragma unroll
                for (int ni = 0; ni < 4; ++ni)
                    acc[mi][ni] = __builtin_amdgcn_mfma_f32_16x16x32_bf16(af[mi], bfv[ni], acc[mi][ni], 0, 0, 0);
        }
        __syncthreads();   // all frag reads done before next stage overwrites
    }

    if constexpr (G1) {
        // h = slot_w * silu(acc)  (weight folded here so gemm2 can atomically combine)
#pragma unroll
        for (int mi = 0; mi < 4; ++mi)
#pragma unroll
            for (int r = 0; r < 4; ++r) {
                const int rl = wm + mi * 16 + lq * 4 + r;
                if (rl < vm) {
                    const float w = slot_w[m0 + rl];
                    u16* hp = hout + (size_t)(m0 + rl) * F_DIM + nt * 128 + wn + lr;
#pragma unroll
                    for (int ni = 0; ni < 4; ++ni) {
                        const float v = acc[mi][ni][r];
                        hp[ni * 16] = f2bf(w * v / (1.0f + __expf(-v)));
                    }
                }
            }
    } else {
#pragma unroll
        for (int mi = 0; mi < 4; ++mi)
#pragma unroll
            for (int r = 0; r < 4; ++r) {
                const int rl = wm + mi * 16 + lq * 4 + r;
                if (rl < vm) {
                    const int tok = slot_tok[m0 + rl];
                    float* op = out + (size_t)tok * D_DIM + nt * 128 + wn + lr;
#pragma unroll
                    for (int ni = 0; ni < 4; ++ni) atomicAdd(&op[ni * 16], acc[mi][ni][r]);
                }
            }
    }
}

extern "C" void kernel_launch(void* const* d_in, const int* in_sizes, int n_in,
                              void* d_out, int out_size, void* d_ws, size_t ws_size,
                              hipStream_t stream) {
    const float* hidden = (const float*)d_in[0];   // [B,S,D] f32
    const float* gl     = (const float*)d_in[1];   // [T,E]   f32
    const float* W1     = (const float*)d_in[2];   // [E,D,F] f32
    const float* W2     = (const float*)d_in[3];   // [E,F,D] f32
    float* out = (float*)d_out;

    char* ws = (char*)d_ws;
    int* m = (int*)ws;
    int* cnt      = m;
    int* basep    = m + 16;
    int* slot_tok = m + 32;                        // 4096 ints
    float* slot_w = (float*)(m + 32 + 4096);       // 4096 floats   (< 64 KB meta)

    const size_t HBYTES  = (size_t)(NSLOT + 128) * F_DIM * 2;        // 17.3 MB (+slack rows)
    const size_t W1BYTES = (size_t)E_N * D_DIM * F_DIM * 2;          // 33.55 MB
    const size_t XBYTES  = (size_t)(NSLOT + 128) * D_DIM * 2;        // 8.65 MB (+slack)
    u16* h   = (u16*)(ws + (1 << 16));
    u16* W1T = (u16*)(ws + (1 << 16) + HBYTES);
    u16* Xg  = (u16*)(ws + (1 << 16) + HBYTES + W1BYTES);
    u16* W2T = (u16*)(ws + (1 << 16) + HBYTES + W1BYTES + XBYTES);   // total ~93.1 MB

    hipMemsetAsync(d_out, 0, (size_t)out_size * sizeof(float), stream);
    router_kernel<<<1, 256, 0, stream>>>(gl, cnt, basep, slot_tok, slot_w);
    prep_kernel<<<8192 + NSLOT / 4, 256, 0, stream>>>(W1, W2, hidden, slot_tok, W1T, W2T, Xg);
    moe_gemm_kernel<true><<<dim3(F_DIM / 128, 16, E_N), 256, 0, stream>>>(
        Xg, W1T, cnt, basep, slot_tok, slot_w, h, nullptr);
    moe_gemm_kernel<false><<<dim3(D_DIM / 128, 16, E_N * 2), 256, 0, stream>>>(
        h, W2T, cnt, basep, slot_tok, slot_w, nullptr, out);
}

// Round 6
// 258.931 us; speedup vs baseline: 1.1498x; 1.0299x over previous
//
#include <hip/hip_runtime.h>
#include <hip/hip_bf16.h>

#define E_N 8
#define D_DIM 1024
#define F_DIM 2048
#define T_N 2048
#define NSLOT 4096

typedef unsigned short u16;
typedef unsigned int u32;
typedef unsigned long long u64;
typedef float floatx4 __attribute__((ext_vector_type(4)));
typedef short bf16x8v __attribute__((ext_vector_type(8)));

__device__ __forceinline__ u16 f2bf(float f) {
    union { float f; u32 u; } v; v.f = f;
    u32 r = v.u + 0x7FFFu + ((v.u >> 16) & 1u);   // RNE
    return (u16)(r >> 16);
}

// async global->LDS, 16B per lane; LDS dest = wave-uniform base + lane*16
__device__ __forceinline__ void gll16(const void* g, void* l) {
    __builtin_amdgcn_global_load_lds((const __attribute__((address_space(1))) void*)g,
                                     (__attribute__((address_space(3))) void*)l, 16, 0, 0);
}

// ---------------- K1 Router: 8 blocks x 256 threads, 1 token/thread, no global atomics ----
// Per-block LDS counts give local ranks; global slot computed later from bcnt prefix.
__global__ __launch_bounds__(256) void router_kernel(const float* __restrict__ gl,
                                                     int4* __restrict__ tok_meta,
                                                     float* __restrict__ tok_w0,
                                                     int* __restrict__ bcnt) {
    __shared__ int scnt[E_N];
    const int tid = threadIdx.x, b = blockIdx.x;
    if (tid < E_N) scnt[tid] = 0;
    __syncthreads();
    const int t = b * 256 + tid;
    const float4* gp = (const float4*)(gl + (size_t)t * E_N);
    const float4 x0 = gp[0], x1 = gp[1];
    float l[E_N] = {x0.x, x0.y, x0.z, x0.w, x1.x, x1.y, x1.z, x1.w};
    int e0 = 0; float m0 = l[0];
#pragma unroll
    for (int e = 1; e < E_N; ++e) if (l[e] > m0) { m0 = l[e]; e0 = e; }
    int e1 = -1; float m1 = -1e30f;
#pragma unroll
    for (int e = 0; e < E_N; ++e) if (e != e0 && l[e] > m1) { m1 = l[e]; e1 = e; }
    const float p = __expf(m1 - m0);            // <= 1
    const float w0 = 1.0f / (1.0f + p);
    const int r0 = atomicAdd(&scnt[e0], 1);
    const int r1 = atomicAdd(&scnt[e1], 1);
    tok_meta[t] = make_int4(e0, e1, r0, r1);
    tok_w0[t] = w0;
    __syncthreads();
    if (tid < E_N) bcnt[b * E_N + tid] = scnt[tid];
}

// ---------------- cvt+transpose tile-PAIR (64 rows x 128 cols) via LDS, pipelined ----------
// 8 float4 loads in flight up-front; tile1 processed after tile0 (separate LDS region).
// LT region per tile: 64 cols x 144 B; elem (c,r) at c*144 + ((r>>2)^(c&15... ) see below.
__device__ __forceinline__ void cvt_pair(const float* __restrict__ src, u16* __restrict__ dst,
                                         int R, int C, int tr, int tcp, int e, char* LT) {
    const int r0 = tr << 6, c0 = tcp << 7;
    const int t = threadIdx.x;
    const int rowq = t >> 4, col4 = t & 15;
    const float* sp = src + (size_t)e * R * C + (size_t)(r0 + rowq * 4) * C + c0 + col4 * 4;
    float4 v0[4], v1[4];
#pragma unroll
    for (int i = 0; i < 4; ++i) v0[i] = *(const float4*)(sp + (size_t)i * C);
#pragma unroll
    for (int i = 0; i < 4; ++i) v1[i] = *(const float4*)(sp + (size_t)i * C + 64);
    u16* dp = dst + (size_t)e * R * C;

    // tile 0 write
    const float* f0 = (const float*)v0;
#pragma unroll
    for (int j = 0; j < 4; ++j) {
        const int c = col4 * 4 + j;
        u64 pk = (u64)f2bf(f0[0 * 4 + j]) | ((u64)f2bf(f0[1 * 4 + j]) << 16)
               | ((u64)f2bf(f0[2 * 4 + j]) << 32) | ((u64)f2bf(f0[3 * 4 + j]) << 48);
        *(u64*)(LT + c * 144 + ((rowq ^ col4) << 3)) = pk;
    }
    __syncthreads();
    // tile 0 read+store  (and tile 1 write, disjoint LDS region)
#pragma unroll
    for (int i = 0; i < 2; ++i) {
        const int id = i * 256 + t;
        const int c = id >> 3, seg = id & 7;
        const int x = (c >> 2) & 15;
        u64 q[2];
        q[0] = *(const u64*)(LT + c * 144 + (((2 * seg) ^ x) << 3));
        q[1] = *(const u64*)(LT + c * 144 + (((2 * seg + 1) ^ x) << 3));
        *(uint4*)(dp + (size_t)(c0 + c) * R + r0 + seg * 8) = *(const uint4*)q;
    }
    const float* f1 = (const float*)v1;
#pragma unroll
    for (int j = 0; j < 4; ++j) {
        const int c = col4 * 4 + j;
        u64 pk = (u64)f2bf(f1[0 * 4 + j]) | ((u64)f2bf(f1[1 * 4 + j]) << 16)
               | ((u64)f2bf(f1[2 * 4 + j]) << 32) | ((u64)f2bf(f1[3 * 4 + j]) << 48);
        *(u64*)(LT + 9216 + c * 144 + ((rowq ^ col4) << 3)) = pk;
    }
    __syncthreads();
    // tile 1 read+store
#pragma unroll
    for (int i = 0; i < 2; ++i) {
        const int id = i * 256 + t;
        const int c = id >> 3, seg = id & 7;
        const int x = (c >> 2) & 15;
        u64 q[2];
        q[0] = *(const u64*)(LT + 9216 + c * 144 + (((2 * seg) ^ x) << 3));
        q[1] = *(const u64*)(LT + 9216 + c * 144 + (((2 * seg + 1) ^ x) << 3));
        *(uint4*)(dp + (size_t)(c0 + 64 + c) * R + r0 + seg * 8) = *(const uint4*)q;
    }
}

// ---------------- K2 Prep: W1^T cvt, W2^T cvt, gather (both slots), zero-out, meta --------
__global__ __launch_bounds__(256) void prep_kernel(
        const float* __restrict__ W1, const float* __restrict__ W2,
        const float* __restrict__ X, float* __restrict__ out,
        const int4* __restrict__ tok_meta, const float* __restrict__ tok_w0,
        const int* __restrict__ bcnt,
        int* __restrict__ cnt, int* __restrict__ basep,
        int* __restrict__ slot_tok, float* __restrict__ slot_w,
        u16* __restrict__ W1T, u16* __restrict__ W2T, u16* __restrict__ Xg) {
    __shared__ __align__(16) char LT[18432];
    __shared__ int sb[64];
    const int b = blockIdx.x;
    const int tid = threadIdx.x;
    if (b < 2048) {                    // W1: R=1024 C=2048; 16 tr x 16 tile-pairs
        const int e = b >> 8, p = b & 255;
        cvt_pair(W1, W1T, D_DIM, F_DIM, p >> 4, p & 15, e, LT);
    } else if (b < 4096) {             // W2: R=2048 C=1024; 32 tr x 8 tile-pairs
        const int b2 = b - 2048;
        const int e = b2 >> 8, p = b2 & 255;
        cvt_pair(W2, W2T, F_DIM, D_DIM, p >> 3, p & 7, e, LT);
    } else if (b < 4608) {             // gather: 4 tokens/block, 1 wave each
        const int g = b - 4096;
        if (tid < 64) sb[tid] = bcnt[tid];
        __syncthreads();
        int cntE[E_N], baseE[E_N];
        {
            int s = 0;
#pragma unroll
            for (int e = 0; e < E_N; ++e) {
                int c = 0;
#pragma unroll
                for (int k = 0; k < 8; ++k) c += sb[k * E_N + e];
                cntE[e] = c; baseE[e] = s; s += c;
            }
        }
        const int t = g * 4 + (tid >> 6), lane = tid & 63;
        const int4 mt = tok_meta[t];
        const float w0 = tok_w0[t];
        const int bt = t >> 8;
        int o0 = baseE[mt.x], o1 = baseE[mt.y];
        for (int k = 0; k < bt; ++k) { o0 += sb[k * E_N + mt.x]; o1 += sb[k * E_N + mt.y]; }
        const int s0 = o0 + mt.z, s1 = o1 + mt.w;
        const float* xp = X + (size_t)t * D_DIM + lane * 4;
        u16* g0 = Xg + (size_t)s0 * D_DIM + lane * 4;
        u16* g1 = Xg + (size_t)s1 * D_DIM + lane * 4;
#pragma unroll
        for (int p = 0; p < 4; ++p) {
            const float4 v = *(const float4*)(xp + p * 256);
            union { u16 o[4]; uint2 q; } u;
            u.o[0] = f2bf(v.x); u.o[1] = f2bf(v.y); u.o[2] = f2bf(v.z); u.o[3] = f2bf(v.w);
            *(uint2*)(g0 + p * 256) = u.q;
            *(uint2*)(g1 + p * 256) = u.q;
        }
        if (lane == 0) {
            slot_tok[s0] = t; slot_tok[s1] = t;
            slot_w[s0] = w0; slot_w[s1] = 1.0f - w0;
        }
        if (g == 0 && tid < E_N) { cnt[tid] = cntE[tid]; basep[tid] = baseE[tid]; }
    } else {                           // zero out: 1024 blocks x 2048 floats
        const int z = b - 4608;
        float4 zq = {0.f, 0.f, 0.f, 0.f};
        float* op = out + (size_t)z * 2048 + tid * 8;
        *(float4*)op = zq;
        *(float4*)(op + 4) = zq;
    }
}

// ---------------- Grouped GEMM, m97 structure + T2 swizzle (single buffer) ----------------
// A: [slots][KA] bf16 row-major. B: B^T rows [N][KB] bf16 (per-expert stride D*F).
// Tile 128x128, BK=64, 4 waves (2x2 of 64x64), 16x16x32 MFMA, 4x4 frags.
template<bool G1>
__global__ __launch_bounds__(256) void moe_gemm_kernel(
        const u16* __restrict__ A, const u16* __restrict__ B,
        const int* __restrict__ cnt, const int* __restrict__ basep,
        const int* __restrict__ slot_tok, const float* __restrict__ slot_w,
        u16* __restrict__ hout, float* __restrict__ out) {
    constexpr int KA = G1 ? D_DIM : F_DIM;   // A row stride (elements)
    constexpr int KB = KA;                   // B^T row stride
    constexpr int KIT = 16;                  // 1024/64 per (split-)K range
    const int e  = G1 ? blockIdx.z : (blockIdx.z >> 1);
    const int kh = G1 ? 0 : (blockIdx.z & 1);
    const int mt = blockIdx.y;
    const int nt = blockIdx.x;
    const int cnt_e = cnt[e];
    if (mt * 128 >= cnt_e) return;
    const int m0 = basep[e] + mt * 128;
    const int vm = cnt_e - mt * 128;

    __shared__ __align__(16) u16 Alds[8192];
    __shared__ __align__(16) u16 Blds[8192];

    const int tid = threadIdx.x;
    const int wid = tid >> 6, lane = tid & 63;
    const int l3 = lane >> 3, l7 = lane & 7;
    const int stgRow = wid * 8 + l3;               // +c*32 per chunk
    const int stgCol = ((l7 ^ l3) << 3);           // pre-swizzled source col (elements)

    const u16* aS = A + (size_t)(m0 + stgRow) * KA + kh * (F_DIM / 2) + stgCol;
    const u16* bS = B + (size_t)e * ((size_t)D_DIM * F_DIM)
                      + (size_t)(nt * 128 + stgRow) * KB + kh * (F_DIM / 2) + stgCol;

    const int wm = (wid >> 1) * 64, wn = (wid & 1) * 64;
    const int lr = lane & 15, lq = lane >> 4;
    const int aoff = (wm + lr) * 64;               // + mi*1024 + sw
    const int boff = (wn + lr) * 64;
    const int sw0 = ((lq)     ^ l7) << 3;          // k-slice 0 swizzled slot
    const int sw1 = ((lq + 4) ^ l7) << 3;          // k-slice 1

    floatx4 acc[4][4];
    const floatx4 zero = {0.f, 0.f, 0.f, 0.f};
#pragma unroll
    for (int i = 0; i < 4; ++i)
#pragma unroll
        for (int j = 0; j < 4; ++j) acc[i][j] = zero;

    for (int kt = 0; kt < KIT; ++kt) {
#pragma unroll
        for (int c = 0; c < 4; ++c) {
            gll16(aS + (size_t)(c * 32) * KA, &Alds[c * 2048 + wid * 512]);
            gll16(bS + (size_t)(c * 32) * KB, &Blds[c * 2048 + wid * 512]);
        }
        aS += 64; bS += 64;
        __syncthreads();   // drains vmcnt -> LDS ready
#pragma unroll
        for (int ks = 0; ks < 2; ++ks) {
            const int sw = ks ? sw1 : sw0;
            bf16x8v af[4], bfv[4];
#pragma unroll
            for (int mi = 0; mi < 4; ++mi) af[mi]  = *(const bf16x8v*)&Alds[aoff + mi * 1024 + sw];
#pragma unroll
            for (int ni = 0; ni < 4; ++ni) bfv[ni] = *(const bf16x8v*)&Blds[boff + ni * 1024 + sw];
#pragma unroll
            for (int mi = 0; mi < 4; ++mi)
#pragma unroll
                for (int ni = 0; ni < 4; ++ni)
                    acc[mi][ni] = __builtin_amdgcn_mfma_f32_16x16x32_bf16(af[mi], bfv[ni], acc[mi][ni], 0, 0, 0);
        }
        __syncthreads();   // all frag reads done before next stage overwrites
    }

    if constexpr (G1) {
        // h = slot_w * silu(acc)  (weight folded here so gemm2 can atomically combine)
#pragma unroll
        for (int mi = 0; mi < 4; ++mi)
#pragma unroll
            for (int r = 0; r < 4; ++r) {
                const int rl = wm + mi * 16 + lq * 4 + r;
                if (rl < vm) {
                    const float w = slot_w[m0 + rl];
                    u16* hp = hout + (size_t)(m0 + rl) * F_DIM + nt * 128 + wn + lr;
#pragma unroll
                    for (int ni = 0; ni < 4; ++ni) {
                        const float v = acc[mi][ni][r];
                        hp[ni * 16] = f2bf(w * v / (1.0f + __expf(-v)));
                    }
                }
            }
    } else {
#pragma unroll
        for (int mi = 0; mi < 4; ++mi)
#pragma unroll
            for (int r = 0; r < 4; ++r) {
                const int rl = wm + mi * 16 + lq * 4 + r;
                if (rl < vm) {
                    const int tok = slot_tok[m0 + rl];
                    float* op = out + (size_t)tok * D_DIM + nt * 128 + wn + lr;
#pragma unroll
                    for (int ni = 0; ni < 4; ++ni) atomicAdd(&op[ni * 16], acc[mi][ni][r]);
                }
            }
    }
}

extern "C" void kernel_launch(void* const* d_in, const int* in_sizes, int n_in,
                              void* d_out, int out_size, void* d_ws, size_t ws_size,
                              hipStream_t stream) {
    const float* hidden = (const float*)d_in[0];   // [B,S,D] f32
    const float* gl     = (const float*)d_in[1];   // [T,E]   f32
    const float* W1     = (const float*)d_in[2];   // [E,D,F] f32
    const float* W2     = (const float*)d_in[3];   // [E,F,D] f32
    float* out = (float*)d_out;

    char* ws = (char*)d_ws;
    int*   cnt      = (int*)(ws + 0);              // 16 ints
    int*   basep    = (int*)(ws + 64);             // 16 ints
    int*   bcnt     = (int*)(ws + 128);            // 64 ints
    int4*  tok_meta = (int4*)(ws + 512);           // 2048 * 16 B = 32 KB
    float* tok_w0   = (float*)(ws + 512 + 32768);  // 8 KB
    int*   slot_tok = (int*)(ws + 512 + 40960);    // 16 KB
    float* slot_w   = (float*)(ws + 512 + 57344);  // 16 KB  (meta ends < 128 KB)

    const size_t META    = 131072;
    const size_t HBYTES  = (size_t)(NSLOT + 128) * F_DIM * 2;        // 17.3 MB (+slack rows)
    const size_t W1BYTES = (size_t)E_N * D_DIM * F_DIM * 2;          // 33.55 MB
    const size_t XBYTES  = (size_t)(NSLOT + 128) * D_DIM * 2;        // 8.65 MB (+slack)
    u16* h   = (u16*)(ws + META);
    u16* W1T = (u16*)(ws + META + HBYTES);
    u16* Xg  = (u16*)(ws + META + HBYTES + W1BYTES);
    u16* W2T = (u16*)(ws + META + HBYTES + W1BYTES + XBYTES);        // total ~93.2 MB

    router_kernel<<<8, 256, 0, stream>>>(gl, tok_meta, tok_w0, bcnt);
    prep_kernel<<<5632, 256, 0, stream>>>(W1, W2, hidden, out, tok_meta, tok_w0, bcnt,
                                          cnt, basep, slot_tok, slot_w, W1T, W2T, Xg);
    moe_gemm_kernel<true><<<dim3(F_DIM / 128, 16, E_N), 256, 0, stream>>>(
        Xg, W1T, cnt, basep, slot_tok, slot_w, h, nullptr);
    moe_gemm_kernel<false><<<dim3(D_DIM / 128, 16, E_N * 2), 256, 0, stream>>>(
        h, W2T, cnt, basep, slot_tok, slot_w, nullptr, out);
}